// Round 20
// baseline (1089.224 us; speedup 1.0000x reference)
//
#include <hip/hip_runtime.h>
#include <math.h>

#define HH 768
#define WW 768
#define NPIX (HH*WW)            // 589824
#define NRR 24
#define NCC 24
#define NCELL (NRR*NCC)         // 576
#define CTOPC 36
#define NB 2

typedef _Float16 f16x8 __attribute__((ext_vector_type(8)));
typedef float f32x4 __attribute__((ext_vector_type(4)));

// xT (f16 [px][ch64], channel-major) lives in spare d_out imgs:
// b0 -> imgs 0..31, b1 -> imgs 54..85. Conv outputs imgs 36..53 / 91..108
// are disjoint; bcast overwrites the temp region only after consumption.
__device__ __forceinline__ size_t xt_off(int b) {
  return b ? (size_t)54 * NPIX : 0;    // u32 units
}

// ws layout (u32 units)
#define OFF_WB     0         // 150 B-frags x 256 u32 = 38400
#define OFF_ZP     38400     // 256 u32 zeros
#define OFF_FSUM   38656     // 2*576*18 = 20736 floats
#define OFF_BOTP   59392     // 1152
#define OFF_TMEAN  60544     // 41472
#define OFF_PVAL   102016    // 576
#define OFF_BOUNDS 102592    // 96 ints

// ---------------- Kernel 0: B-fragment weight pack + bounds + zp ----------------
__global__ void prep_kernel(const float* __restrict__ w1, const float* __restrict__ w2,
                            const float* __restrict__ w3,
                            const int* __restrict__ row_ids, const int* __restrict__ col_ids,
                            unsigned int* __restrict__ wB, unsigned int* __restrict__ zp,
                            int* __restrict__ bounds) {
  int t = blockIdx.x * 256 + threadIdx.x;
  if (t < 150 * 256) {
    int frag = t >> 8, r = t & 255;
    int lane = r >> 2, part = r & 3;
    int chb = frag & 1, q = frag >> 1;     // q = d*25 + tap
    int d = q / 25, tap = q % 25;
    int ky = tap / 5, kx = tap % 5;
    int oc = lane & 15;
    int kk = (lane >> 4) * 8 + part * 2;
    int ch0 = chb * 32 + kk, ch1 = ch0 + 1;
    const float* ws_ = (d == 0) ? w1 : ((d == 1) ? w2 : w3);
    float f0 = (oc < 6 && ch0 < 55) ? ws_[((oc * 55 + ch0) * 5 + ky) * 5 + kx] : 0.f;
    float f1 = (oc < 6 && ch1 < 55) ? ws_[((oc * 55 + ch1) * 5 + ky) * 5 + kx] : 0.f;
    _Float16 g0 = (_Float16)f0, g1 = (_Float16)f1;   // RTNE
    wB[t] = (unsigned int)__builtin_bit_cast(unsigned short, g0) |
            ((unsigned int)__builtin_bit_cast(unsigned short, g1) << 16);
  }
  if (blockIdx.x == 1 && threadIdx.x < 256) zp[threadIdx.x] = 0u;
  if (blockIdx.x == 0 && threadIdx.x < 48) {
    int tt = threadIdx.x;
    const int* ids = (tt < 24) ? row_ids : col_ids;
    int r = tt % 24;
    int s = HH, e = HH;
    for (int h = 0; h < HH; ++h) {
      int v = ids[h];
      if (v >= r && h < s) s = h;
      if (v >= r + 1 && h < e) e = h;
    }
    int base = (tt < 24) ? 0 : 48;
    bounds[base + r] = s;
    bounds[base + 24 + r] = e;
  }
}

// ---------------- Kernel T: fp32 x [ch][px] -> f16 xT [px][ch64] ----------------
__global__ __launch_bounds__(256) void xpose_kernel(const float* __restrict__ x,
                                                    unsigned int* __restrict__ outU) {
  const int b = blockIdx.y;
  const int px = blockIdx.x * 256 + threadIdx.x;
  const float* xb = x + (size_t)b * 55 * NPIX + px;
  unsigned int buf[32];
  #pragma unroll
  for (int cp = 0; cp < 27; ++cp) {
    float f0 = xb[(size_t)(2 * cp) * NPIX];
    float f1 = xb[(size_t)(2 * cp + 1) * NPIX];
    buf[cp] = __builtin_bit_cast(unsigned int, __builtin_amdgcn_cvt_pkrtz(f0, f1));
  }
  buf[27] = __builtin_bit_cast(unsigned int, __builtin_amdgcn_cvt_pkrtz(xb[(size_t)54 * NPIX], 0.f));
  buf[28] = buf[29] = buf[30] = buf[31] = 0u;
  unsigned int* dst = outU + xt_off(b) + (size_t)px * 32;
  #pragma unroll
  for (int i = 0; i < 8; ++i) ((uint4*)dst)[i] = *(uint4*)&buf[i * 4];
}

// ---------------- Kernel A: MFMA implicit-GEMM conv, single-buffer 4-blocks/CU ----------------
// 384 thr = 6 waves = (3 dil) x (2 h-halves). Tile 16w x 8h x 18oc.
// r19 failure: waves_per_eu(2,6) -> allocator settled at VGPR=128 (4 waves/EU)
// -> 16 waves/CU cap -> occupancy stuck 17%. Fix: waves_per_eu(6,6) FORCES
// VGPR <= 85 (r18's near-identical code fit in 84). Then LDS (35.8 KB -> 4
// blocks/CU) and VGPR (6 waves/SIMD) both allow 24 waves/CU: cross-block
// stagger hides the DS-latency gap (floor ~216us).
// Staging via global_load_lds, swizzle on the SOURCE address (rule #21);
// read uses the same XOR (verified r16: conflicts 5.3e7 -> 4.4e6).
__global__ __attribute__((amdgpu_flat_work_group_size(384, 384)))
           __attribute__((amdgpu_waves_per_eu(6, 6)))
void conv_kernel(const unsigned int* __restrict__ outU_c,
                 const unsigned int* __restrict__ wB,
                 const unsigned int* __restrict__ zp,
                 const float* __restrict__ b1, const float* __restrict__ b2,
                 const float* __restrict__ b3, float* __restrict__ out) {
  __shared__ __align__(16) unsigned int tile[8960];   // [560 px][16 u32] = 35.8 KB
  const int tid = threadIdx.x;
  const int lane = tid & 63, wave = tid >> 6;
  const int d = wave >> 1, hh = wave & 1, dil = d + 1;
  const int b = blockIdx.z;
  const int h0 = blockIdx.y * 8, w0 = blockIdx.x * 16;
  const unsigned int* xTb = outU_c + xt_off(b);
  const int col = lane & 15, kq = lane >> 4;

  auto STAGE = [&](int chb) {
    #pragma unroll
    for (int k = 0; k < 6; ++k) {
      int idx = k * 384 + tid;              // 16B-chunk index, 2240 total
      if (idx < 2240) {                     // wave-uniform guard (2240 = 35 waves)
        int pxl = idx >> 2, slot = idx & 3;
        int q = slot ^ ((pxl >> 1) & 3);    // inverse swizzle on the SOURCE
        int th = pxl / 28, tw = pxl % 28;
        int gh = h0 - 6 + th, gw = w0 - 6 + tw;
        bool ok = ((unsigned)gh < 768u) & ((unsigned)gw < 768u);
        const unsigned int* src = ok
            ? xTb + ((size_t)(gh * 768 + gw)) * 32 + chb * 16 + q * 4
            : zp + (lane) * 4;
        unsigned int* dst = &tile[(k * 384 + (tid & ~63)) * 4];  // wave-uniform base
        __builtin_amdgcn_global_load_lds(
            (const __attribute__((address_space(1))) void*)src,
            (__attribute__((address_space(3))) void*)dst, 16, 0, 0);
      }
    }
  };

  f32x4 acc[4];
  #pragma unroll
  for (int u = 0; u < 4; ++u) acc[u] = (f32x4){0.f, 0.f, 0.f, 0.f};

  auto COMPUTE = [&](int chb) {
    const unsigned int* tb = &tile[0];
    const unsigned int* wBc = wB + d * 12800 + chb * 256;   // tap stride 512 u32
    uint4 bf = *(const uint4*)(wBc + lane * 4);
    #pragma unroll
    for (int tap = 0; tap < 25; ++tap) {
      uint4 bfn = bf;
      if (tap < 24) bfn = *(const uint4*)(wBc + (size_t)(tap + 1) * 512 + lane * 4);
      const int ky = tap / 5, kx = tap % 5;
      const int dy = (ky - 2) * dil, dx = (kx - 2) * dil;
      const int thb = hh * 4 + 6 + dy;
      const int twb = col + 6 + dx;
      f16x8 bfrag = __builtin_bit_cast(f16x8, bf);
      __builtin_amdgcn_s_setprio(1);
      #pragma unroll
      for (int u = 0; u < 4; ++u) {
        int pxl = (thb + u) * 28 + twb;
        int slot = kq ^ ((pxl >> 1) & 3);
        f16x8 afrag = __builtin_bit_cast(f16x8, *(const uint4*)&tb[pxl * 16 + slot * 4]);
        acc[u] = __builtin_amdgcn_mfma_f32_16x16x32_f16(afrag, bfrag, acc[u], 0, 0, 0);
      }
      __builtin_amdgcn_s_setprio(0);
      bf = bfn;
    }
  };

  STAGE(0);
  __syncthreads();          // drains stage0
  COMPUTE(0);
  __syncthreads();          // all reads of buf done
  STAGE(1);
  __syncthreads();          // drains stage1
  COMPUTE(1);
  __syncthreads();

  // ---- epilogue: C-frags (row=px=(lane>>4)*4+reg, col=oc) -> LDS -> global
  float* ot = (float*)&tile[0];             // 2304 f32
  if (col < 6) {
    #pragma unroll
    for (int u = 0; u < 4; ++u) {
      int row = hh * 4 + u;
      int oc = d * 6 + col;
      #pragma unroll
      for (int reg = 0; reg < 4; ++reg) {
        int px = kq * 4 + reg;
        ot[(oc * 8 + row) * 16 + px] = acc[u][reg];
      }
    }
  }
  __syncthreads();
  #pragma unroll
  for (int k = 0; k < 2; ++k) {
    int i = k * 384 + tid;                // float4 index, 576 total
    if (i < 576) {
      int oc = i >> 5, rem = i & 31;
      int row = rem >> 2, f4 = rem & 3;
      float bias = oc < 6 ? b1[oc] : (oc < 12 ? b2[oc - 6] : b3[oc - 12]);
      float4 v = ((float4*)ot)[i];
      v.x = fmaxf(v.x + bias, 0.f); v.y = fmaxf(v.y + bias, 0.f);
      v.z = fmaxf(v.z + bias, 0.f); v.w = fmaxf(v.w + bias, 0.f);
      *(float4*)(out + ((size_t)(b * 55 + 36 + oc)) * NPIX
                 + (size_t)(h0 + row) * 768 + w0 + f4 * 4) = v;
    }
  }
}

// ---------------- Kernel B: per-cell sums of features + sigmoid(bot) ----------------
__global__ __launch_bounds__(256) void cellsum_kernel(const float* __restrict__ dout,
    const int* __restrict__ bounds,
    const float* __restrict__ w_bot, const float* __restrict__ b_bot,
    float* __restrict__ feat_sums, float* __restrict__ bot_partial) {
  int blk = blockIdx.x;                       // b*576 + r*24 + c
  int b = blk / NCELL; int rc = blk % NCELL; int r = rc / NCC, c = rc % NCC;
  int rs = bounds[r], re = bounds[24 + r], cs = bounds[48 + c], ce = bounds[72 + c];
  int cw = ce - cs;
  int npix = (re - rs) * cw;
  float facc[18];
  #pragma unroll
  for (int k = 0; k < 18; ++k) facc[k] = 0.f;
  float sacc = 0.f;
  float wb[18];
  #pragma unroll
  for (int k = 0; k < 18; ++k) wb[k] = w_bot[k];
  float bb = b_bot[0];
  const float* fb = dout + ((size_t)b * 55 + 36) * NPIX;
  for (int i = threadIdx.x; i < npix; i += 256) {
    int hh = rs + i / cw, ww = cs + i % cw;
    int pix = hh * WW + ww;
    float dot = bb;
    #pragma unroll
    for (int k = 0; k < 18; ++k) {
      float v = fb[(size_t)k * NPIX + pix];
      facc[k] += v;
      dot += wb[k] * v;
    }
    sacc += 1.f / (1.f + expf(-dot));
  }
  #pragma unroll
  for (int k = 0; k < 18; ++k) {
    #pragma unroll
    for (int off = 32; off; off >>= 1) facc[k] += __shfl_xor(facc[k], off);
  }
  #pragma unroll
  for (int off = 32; off; off >>= 1) sacc += __shfl_xor(sacc, off);
  __shared__ float red[4][19];
  int wv = threadIdx.x >> 6, ln = threadIdx.x & 63;
  if (ln == 0) {
    #pragma unroll
    for (int k = 0; k < 18; ++k) red[wv][k] = facc[k];
    red[wv][18] = sacc;
  }
  __syncthreads();
  if (threadIdx.x < 19) {
    float s = red[0][threadIdx.x] + red[1][threadIdx.x] + red[2][threadIdx.x] + red[3][threadIdx.x];
    if (threadIdx.x < 18) feat_sums[(size_t)blk * 18 + threadIdx.x] = s;
    else bot_partial[blk] = s;
  }
}

// ---------------- Kernel C: cell means (top) + pools ----------------
__global__ void cellmean_kernel(const float* __restrict__ feat_sums,
    const float* __restrict__ bot_partial, const int* __restrict__ bounds,
    const float* __restrict__ w_top, const float* __restrict__ b_top,
    float* __restrict__ top_means, float* __restrict__ pools_val, float* __restrict__ dout) {
  int t = blockIdx.x * 256 + threadIdx.x;
  if (t < NB * CTOPC * NCELL) {
    int c = t % NCC, r = (t / NCC) % NRR, k = (t / NCELL) % CTOPC, b = t / (NCELL * CTOPC);
    int cnt = (bounds[24 + r] - bounds[r]) * (bounds[72 + c] - bounds[48 + c]);
    float v = 0.f;
    if (cnt > 0) {
      const float* fs = feat_sums + ((size_t)(b * NCELL + r * NCC + c)) * 18;
      float dot = 0.f;
      #pragma unroll
      for (int i = 0; i < 18; ++i) dot += w_top[k * 18 + i] * fs[i];
      v = dot / (float)cnt + b_top[k];
    }
    top_means[t] = v;   // [b][k][r][c]
  }
  int t2 = t - NB * CTOPC * NCELL;
  if (t2 >= 0 && t2 < NCELL) {
    int r = t2 / NCC, c = t2 % NCC;
    int cnt = (bounds[24 + r] - bounds[r]) * (bounds[72 + c] - bounds[48 + c]);
    if (cnt < 1) cnt = 1;
    float v = (bot_partial[t2] + bot_partial[NCELL + t2]) / (2.f * (float)cnt);
    pools_val[t2] = v;
    dout[(size_t)NB * 55 * NPIX + t2] = v;           // pools b=0
    dout[(size_t)NB * 55 * NPIX + NCELL + t2] = v;   // pools b=1
  }
}

// ---------------- Kernel D: broadcast top means + bottom value ----------------
__global__ __launch_bounds__(256) void bcast_kernel(const float* __restrict__ top_means,
    const float* __restrict__ pools_val, const int* __restrict__ row_ids,
    const int* __restrict__ col_ids, float* __restrict__ out) {
  int w = blockIdx.x * 256 + threadIdx.x;
  int h = blockIdx.y;
  int b = blockIdx.z;
  int r = row_ids[h], c = col_ids[w];
  int pix = h * 768 + w;
  float* ob = out + (size_t)b * 55 * NPIX + pix;
  const float* tm = top_means + (size_t)b * CTOPC * NCELL + r * NCC + c;
  #pragma unroll
  for (int k = 0; k < 36; ++k) ob[(size_t)k * NPIX] = tm[(size_t)k * NCELL];
  ob[(size_t)54 * NPIX] = pools_val[r * NCC + c];
}

extern "C" void kernel_launch(void* const* d_in, const int* in_sizes, int n_in,
                              void* d_out, int out_size, void* d_ws, size_t ws_size,
                              hipStream_t stream) {
  const float* x      = (const float*)d_in[0];
  const int* row_ids  = (const int*)d_in[1];
  const int* col_ids  = (const int*)d_in[2];
  const float* w1     = (const float*)d_in[5];
  const float* b1     = (const float*)d_in[6];
  const float* w2     = (const float*)d_in[7];
  const float* b2     = (const float*)d_in[8];
  const float* w3     = (const float*)d_in[9];
  const float* b3     = (const float*)d_in[10];
  const float* w_top  = (const float*)d_in[11];
  const float* b_top  = (const float*)d_in[12];
  const float* w_bot  = (const float*)d_in[13];
  const float* b_bot  = (const float*)d_in[14];
  float* out = (float*)d_out;
  float* ws  = (float*)d_ws;

  unsigned int* wB   = (unsigned int*)ws + OFF_WB;
  unsigned int* zp   = (unsigned int*)ws + OFF_ZP;
  float* feat_sums   = ws + OFF_FSUM;
  float* bot_partial = ws + OFF_BOTP;
  float* top_means   = ws + OFF_TMEAN;
  float* pools_val   = ws + OFF_PVAL;
  int*   bounds      = (int*)ws + OFF_BOUNDS;
  unsigned int* outU = (unsigned int*)d_out;

  hipLaunchKernelGGL(prep_kernel, dim3(150), dim3(256), 0, stream,
                     w1, w2, w3, row_ids, col_ids, wB, zp, bounds);
  hipLaunchKernelGGL(xpose_kernel, dim3(2304, 2), dim3(256), 0, stream,
                     x, outU);
  hipLaunchKernelGGL(conv_kernel, dim3(48, 96, 2), dim3(384), 0, stream,
                     outU, wB, zp, b1, b2, b3, out);
  hipLaunchKernelGGL(cellsum_kernel, dim3(NB * NCELL), dim3(256), 0, stream,
                     out, bounds, w_bot, b_bot, feat_sums, bot_partial);
  hipLaunchKernelGGL(cellmean_kernel, dim3(165), dim3(256), 0, stream,
                     feat_sums, bot_partial, bounds, w_top, b_top, top_means, pools_val, out);
  hipLaunchKernelGGL(bcast_kernel, dim3(3, 768, 2), dim3(256), 0, stream,
                     top_means, pools_val, row_ids, col_ids, out);
}

// Round 21
// 453.751 us; speedup vs baseline: 2.4005x; 2.4005x over previous
//
#include <hip/hip_runtime.h>
#include <math.h>

#define HH 768
#define WW 768
#define NPIX (HH*WW)            // 589824
#define NRR 24
#define NCC 24
#define NCELL (NRR*NCC)         // 576
#define CTOPC 36
#define NB 2

typedef _Float16 f16x8 __attribute__((ext_vector_type(8)));
typedef float f32x4 __attribute__((ext_vector_type(4)));

// xT (f16 [px][ch64], channel-major) lives in spare d_out imgs:
// b0 -> imgs 0..31, b1 -> imgs 54..85 (32 imgs = 75.5MB each).
// Conv outputs imgs 36..53 (b0) / 91..108 (b1) are disjoint; bcast overwrites
// imgs 0..35,54 and 55..90,109 only AFTER conv+cellsum consumed everything.
__device__ __forceinline__ size_t xt_off(int b) {
  return b ? (size_t)54 * NPIX : 0;    // u32 units
}

// ws layout (u32 units)
#define OFF_WB     0         // 150 B-frags x 256 u32 = 38400
#define OFF_ZP     38400     // 256 u32 zeros
#define OFF_FSUM   38656     // 2*576*18 = 20736 floats
#define OFF_BOTP   59392     // 1152
#define OFF_TMEAN  60544     // 41472
#define OFF_PVAL   102016    // 576
#define OFF_BOUNDS 102592    // 96 ints

// ---------------- Kernel 0: B-fragment weight pack + bounds + zp ----------------
// Frag (d, tap, chb): lane l holds W[k=(l>>4)*8+j][col=l&15] with
// k -> ch = chb*32 + k, col -> oc (0..5 real, rest zero). 4 u32/lane, 1KB/frag.
__global__ void prep_kernel(const float* __restrict__ w1, const float* __restrict__ w2,
                            const float* __restrict__ w3,
                            const int* __restrict__ row_ids, const int* __restrict__ col_ids,
                            unsigned int* __restrict__ wB, unsigned int* __restrict__ zp,
                            int* __restrict__ bounds) {
  int t = blockIdx.x * 256 + threadIdx.x;
  if (t < 150 * 256) {
    int frag = t >> 8, r = t & 255;
    int lane = r >> 2, part = r & 3;
    int chb = frag & 1, q = frag >> 1;     // q = d*25 + tap
    int d = q / 25, tap = q % 25;
    int ky = tap / 5, kx = tap % 5;
    int oc = lane & 15;
    int kk = (lane >> 4) * 8 + part * 2;
    int ch0 = chb * 32 + kk, ch1 = ch0 + 1;
    const float* ws_ = (d == 0) ? w1 : ((d == 1) ? w2 : w3);
    float f0 = (oc < 6 && ch0 < 55) ? ws_[((oc * 55 + ch0) * 5 + ky) * 5 + kx] : 0.f;
    float f1 = (oc < 6 && ch1 < 55) ? ws_[((oc * 55 + ch1) * 5 + ky) * 5 + kx] : 0.f;
    _Float16 g0 = (_Float16)f0, g1 = (_Float16)f1;   // RTNE
    wB[t] = (unsigned int)__builtin_bit_cast(unsigned short, g0) |
            ((unsigned int)__builtin_bit_cast(unsigned short, g1) << 16);
  }
  if (blockIdx.x == 1 && threadIdx.x < 256) zp[threadIdx.x] = 0u;
  if (blockIdx.x == 0 && threadIdx.x < 48) {
    int tt = threadIdx.x;
    const int* ids = (tt < 24) ? row_ids : col_ids;
    int r = tt % 24;
    int s = HH, e = HH;
    for (int h = 0; h < HH; ++h) {
      int v = ids[h];
      if (v >= r && h < s) s = h;
      if (v >= r + 1 && h < e) e = h;
    }
    int base = (tt < 24) ? 0 : 48;
    bounds[base + r] = s;
    bounds[base + 24 + r] = e;
  }
}

// ---------------- Kernel T: fp32 x [ch][px] -> f16 xT [px][ch64] ----------------
__global__ __launch_bounds__(256) void xpose_kernel(const float* __restrict__ x,
                                                    unsigned int* __restrict__ outU) {
  const int b = blockIdx.y;
  const int px = blockIdx.x * 256 + threadIdx.x;
  const float* xb = x + (size_t)b * 55 * NPIX + px;
  unsigned int buf[32];
  #pragma unroll
  for (int cp = 0; cp < 27; ++cp) {
    float f0 = xb[(size_t)(2 * cp) * NPIX];
    float f1 = xb[(size_t)(2 * cp + 1) * NPIX];
    buf[cp] = __builtin_bit_cast(unsigned int, __builtin_amdgcn_cvt_pkrtz(f0, f1));
  }
  buf[27] = __builtin_bit_cast(unsigned int, __builtin_amdgcn_cvt_pkrtz(xb[(size_t)54 * NPIX], 0.f));
  buf[28] = buf[29] = buf[30] = buf[31] = 0u;
  unsigned int* dst = outU + xt_off(b) + (size_t)px * 32;
  #pragma unroll
  for (int i = 0; i < 8; ++i) ((uint4*)dst)[i] = *(uint4*)&buf[i * 4];
}

// ---------------- Kernel A: MFMA implicit-GEMM conv ----------------
// 384 thr = 6 waves = (3 dil) x (2 h-halves). Tile 32w x 8h x 18oc.
// Per (dil,tap,chb): C[16px,6oc] += Xpatch[16px,32ch] x W[32ch,6oc]
// via mfma_f32_16x16x32_f16. B-frag from global (L2-hot, no DS cost),
// reused over 8 A-tiles -> 1.125 ds_read_b128/MFMA.
// LDS tile [20h][44w][32ch +4pad u32] = 68.75 KB -> 2 blocks/CU.
// MEASURED OPTIMUM (r15-r20 frontier): VGPR 68 / conv ~302us. Swizzle (r16),
// async-dbuf (r18), forced-occupancy (r19/r20: VGPR clamp -> spill) all
// regressed. DS floor ~226us (1 ds_read_b128/MFMA is structural).
__global__ __attribute__((amdgpu_flat_work_group_size(384, 384)))
           __attribute__((amdgpu_waves_per_eu(2, 3)))
void conv_kernel(const unsigned int* __restrict__ outU_c,
                 const unsigned int* __restrict__ wB,
                 const unsigned int* __restrict__ zp,
                 const float* __restrict__ b1, const float* __restrict__ b2,
                 const float* __restrict__ b3, float* __restrict__ out) {
  __shared__ __align__(16) unsigned int tile[17600];   // [880 px][20 u32] (16 data + 4 pad)
  const int tid = threadIdx.x;
  const int lane = tid & 63, wave = tid >> 6;
  const int d = wave >> 1, hh = wave & 1, dil = d + 1;
  const int b = blockIdx.z;
  const int h0 = blockIdx.y * 8, w0 = blockIdx.x * 32;
  const unsigned int* xTb = outU_c + xt_off(b);
  const int col = lane & 15, kq = lane >> 4;

  f32x4 acc[8];
  #pragma unroll
  for (int u = 0; u < 8; ++u) acc[u] = (f32x4){0.f, 0.f, 0.f, 0.f};

  for (int chb = 0; chb < 2; ++chb) {
    // ---- stage [20h][44w][32ch] f16 (px-stride 80B, 2-way-free banks) ----
    #pragma unroll
    for (int k = 0; k < 10; ++k) {
      int idx = k * 384 + tid;
      if (idx < 3520) {                     // 880 px * 4 16B-pieces
        int pxl = idx >> 2, part = idx & 3;
        int th = pxl / 44, tw = pxl % 44;
        int gh = h0 - 6 + th, gw = w0 - 6 + tw;
        bool ok = ((unsigned)gh < 768u) & ((unsigned)gw < 768u);
        const unsigned int* src = ok
            ? xTb + ((size_t)(gh * 768 + gw)) * 32 + chb * 16 + part * 4
            : zp + (tid & 63) * 4;
        uint4 v = *(const uint4*)src;
        *(uint4*)&tile[pxl * 20 + part * 4] = v;
      }
    }
    __syncthreads();
    // ---- compute: 25 taps x 8 units ----
    for (int ky = 0; ky < 5; ++ky) {
      #pragma unroll
      for (int kx = 0; kx < 5; ++kx) {
        const int fidx = ((d * 25 + ky * 5 + kx) * 2 + chb) << 8;
        f16x8 bfrag = __builtin_bit_cast(f16x8, *(const uint4*)(wB + fidx + lane * 4));
        const int dy = (ky - 2) * dil, dx = (kx - 2) * dil;
        const int thb = hh * 4 + 6 + dy;
        const int twb = col + 6 + dx;
        #pragma unroll
        for (int u = 0; u < 8; ++u) {
          int hr = u >> 1, pc = u & 1;
          int a_addr = ((thb + hr) * 44 + twb + pc * 16) * 20 + kq * 4;
          f16x8 afrag = __builtin_bit_cast(f16x8, *(const uint4*)&tile[a_addr]);
          acc[u] = __builtin_amdgcn_mfma_f32_16x16x32_f16(afrag, bfrag, acc[u], 0, 0, 0);
        }
      }
    }
    __syncthreads();
  }

  // ---- epilogue: C-frags (row=px=(lane>>4)*4+reg, col=oc=lane&15) -> LDS -> global
  float* ot = (float*)tile;
  if (col < 6) {
    #pragma unroll
    for (int u = 0; u < 8; ++u) {
      int hr = hh * 4 + (u >> 1), pc = u & 1;
      int oc = d * 6 + col;
      #pragma unroll
      for (int reg = 0; reg < 4; ++reg) {
        int px = kq * 4 + reg;
        ot[(oc * 8 + hr) * 32 + pc * 16 + px] = acc[u][reg];
      }
    }
  }
  __syncthreads();
  #pragma unroll
  for (int k = 0; k < 3; ++k) {
    int i = k * 384 + tid;                // float4 index, 1152 total
    int oc = i >> 6, rem = i & 63;
    int hr = rem >> 3, f4 = rem & 7;
    float bias = oc < 6 ? b1[oc] : (oc < 12 ? b2[oc - 6] : b3[oc - 12]);
    float4 v = ((float4*)ot)[i];
    v.x = fmaxf(v.x + bias, 0.f); v.y = fmaxf(v.y + bias, 0.f);
    v.z = fmaxf(v.z + bias, 0.f); v.w = fmaxf(v.w + bias, 0.f);
    *(float4*)(out + ((size_t)(b * 55 + 36 + oc)) * NPIX
               + (size_t)(h0 + hr) * 768 + w0 + f4 * 4) = v;
  }
}

// ---------------- Kernel B: per-cell sums of features + sigmoid(bot) ----------------
__global__ __launch_bounds__(256) void cellsum_kernel(const float* __restrict__ dout,
    const int* __restrict__ bounds,
    const float* __restrict__ w_bot, const float* __restrict__ b_bot,
    float* __restrict__ feat_sums, float* __restrict__ bot_partial) {
  int blk = blockIdx.x;                       // b*576 + r*24 + c
  int b = blk / NCELL; int rc = blk % NCELL; int r = rc / NCC, c = rc % NCC;
  int rs = bounds[r], re = bounds[24 + r], cs = bounds[48 + c], ce = bounds[72 + c];
  int cw = ce - cs;
  int npix = (re - rs) * cw;
  float facc[18];
  #pragma unroll
  for (int k = 0; k < 18; ++k) facc[k] = 0.f;
  float sacc = 0.f;
  float wb[18];
  #pragma unroll
  for (int k = 0; k < 18; ++k) wb[k] = w_bot[k];
  float bb = b_bot[0];
  const float* fb = dout + ((size_t)b * 55 + 36) * NPIX;
  for (int i = threadIdx.x; i < npix; i += 256) {
    int hh = rs + i / cw, ww = cs + i % cw;
    int pix = hh * WW + ww;
    float dot = bb;
    #pragma unroll
    for (int k = 0; k < 18; ++k) {
      float v = fb[(size_t)k * NPIX + pix];
      facc[k] += v;
      dot += wb[k] * v;
    }
    sacc += 1.f / (1.f + expf(-dot));
  }
  #pragma unroll
  for (int k = 0; k < 18; ++k) {
    #pragma unroll
    for (int off = 32; off; off >>= 1) facc[k] += __shfl_xor(facc[k], off);
  }
  #pragma unroll
  for (int off = 32; off; off >>= 1) sacc += __shfl_xor(sacc, off);
  __shared__ float red[4][19];
  int wv = threadIdx.x >> 6, ln = threadIdx.x & 63;
  if (ln == 0) {
    #pragma unroll
    for (int k = 0; k < 18; ++k) red[wv][k] = facc[k];
    red[wv][18] = sacc;
  }
  __syncthreads();
  if (threadIdx.x < 19) {
    float s = red[0][threadIdx.x] + red[1][threadIdx.x] + red[2][threadIdx.x] + red[3][threadIdx.x];
    if (threadIdx.x < 18) feat_sums[(size_t)blk * 18 + threadIdx.x] = s;
    else bot_partial[blk] = s;
  }
}

// ---------------- Kernel C: cell means (top) + pools ----------------
__global__ void cellmean_kernel(const float* __restrict__ feat_sums,
    const float* __restrict__ bot_partial, const int* __restrict__ bounds,
    const float* __restrict__ w_top, const float* __restrict__ b_top,
    float* __restrict__ top_means, float* __restrict__ pools_val, float* __restrict__ dout) {
  int t = blockIdx.x * 256 + threadIdx.x;
  if (t < NB * CTOPC * NCELL) {
    int c = t % NCC, r = (t / NCC) % NRR, k = (t / NCELL) % CTOPC, b = t / (NCELL * CTOPC);
    int cnt = (bounds[24 + r] - bounds[r]) * (bounds[72 + c] - bounds[48 + c]);
    float v = 0.f;
    if (cnt > 0) {
      const float* fs = feat_sums + ((size_t)(b * NCELL + r * NCC + c)) * 18;
      float dot = 0.f;
      #pragma unroll
      for (int i = 0; i < 18; ++i) dot += w_top[k * 18 + i] * fs[i];
      v = dot / (float)cnt + b_top[k];
    }
    top_means[t] = v;   // [b][k][r][c]
  }
  int t2 = t - NB * CTOPC * NCELL;
  if (t2 >= 0 && t2 < NCELL) {
    int r = t2 / NCC, c = t2 % NCC;
    int cnt = (bounds[24 + r] - bounds[r]) * (bounds[72 + c] - bounds[48 + c]);
    if (cnt < 1) cnt = 1;
    float v = (bot_partial[t2] + bot_partial[NCELL + t2]) / (2.f * (float)cnt);
    pools_val[t2] = v;
    dout[(size_t)NB * 55 * NPIX + t2] = v;           // pools b=0
    dout[(size_t)NB * 55 * NPIX + NCELL + t2] = v;   // pools b=1
  }
}

// ---------------- Kernel D: broadcast top means + bottom value ----------------
__global__ __launch_bounds__(256) void bcast_kernel(const float* __restrict__ top_means,
    const float* __restrict__ pools_val, const int* __restrict__ row_ids,
    const int* __restrict__ col_ids, float* __restrict__ out) {
  int w = blockIdx.x * 256 + threadIdx.x;
  int h = blockIdx.y;
  int b = blockIdx.z;
  int r = row_ids[h], c = col_ids[w];
  int pix = h * 768 + w;
  float* ob = out + (size_t)b * 55 * NPIX + pix;
  const float* tm = top_means + (size_t)b * CTOPC * NCELL + r * NCC + c;
  #pragma unroll
  for (int k = 0; k < 36; ++k) ob[(size_t)k * NPIX] = tm[(size_t)k * NCELL];
  ob[(size_t)54 * NPIX] = pools_val[r * NCC + c];
}

extern "C" void kernel_launch(void* const* d_in, const int* in_sizes, int n_in,
                              void* d_out, int out_size, void* d_ws, size_t ws_size,
                              hipStream_t stream) {
  const float* x      = (const float*)d_in[0];
  const int* row_ids  = (const int*)d_in[1];
  const int* col_ids  = (const int*)d_in[2];
  const float* w1     = (const float*)d_in[5];
  const float* b1     = (const float*)d_in[6];
  const float* w2     = (const float*)d_in[7];
  const float* b2     = (const float*)d_in[8];
  const float* w3     = (const float*)d_in[9];
  const float* b3     = (const float*)d_in[10];
  const float* w_top  = (const float*)d_in[11];
  const float* b_top  = (const float*)d_in[12];
  const float* w_bot  = (const float*)d_in[13];
  const float* b_bot  = (const float*)d_in[14];
  float* out = (float*)d_out;
  float* ws  = (float*)d_ws;

  unsigned int* wB   = (unsigned int*)ws + OFF_WB;
  unsigned int* zp   = (unsigned int*)ws + OFF_ZP;
  float* feat_sums   = ws + OFF_FSUM;
  float* bot_partial = ws + OFF_BOTP;
  float* top_means   = ws + OFF_TMEAN;
  float* pools_val   = ws + OFF_PVAL;
  int*   bounds      = (int*)ws + OFF_BOUNDS;
  unsigned int* outU = (unsigned int*)d_out;

  hipLaunchKernelGGL(prep_kernel, dim3(150), dim3(256), 0, stream,
                     w1, w2, w3, row_ids, col_ids, wB, zp, bounds);
  hipLaunchKernelGGL(xpose_kernel, dim3(2304, 2), dim3(256), 0, stream,
                     x, outU);
  hipLaunchKernelGGL(conv_kernel, dim3(24, 96, 2), dim3(384), 0, stream,
                     outU, wB, zp, b1, b2, b3, out);
  hipLaunchKernelGGL(cellsum_kernel, dim3(NB * NCELL), dim3(256), 0, stream,
                     out, bounds, w_bot, b_bot, feat_sums, bot_partial);
  hipLaunchKernelGGL(cellmean_kernel, dim3(165), dim3(256), 0, stream,
                     feat_sums, bot_partial, bounds, w_top, b_top, top_means, pools_val, out);
  hipLaunchKernelGGL(bcast_kernel, dim3(3, 768, 2), dim3(256), 0, stream,
                     top_means, pools_val, row_ids, col_ids, out);
}